// Round 2
// baseline (141.045 us; speedup 1.0000x reference)
//
#include <hip/hip_runtime.h>

// ---------------------------------------------------------------------------
// GCNN Double-Q critic, MI355X (gfx950).
// Per batch (4096): A = normalized dense 16x16 adjacency (symmetric); per Q:
//   z0 = A@x ; h1 = relu(z0@W0+b0); z1 = A@h1; h2 = relu(z1@W1+b1);
//   q  = A@(h2@W2) + b2
// GEMMs via mfma_f32_16x16x32_bf16, split-precision (hi+lo) bf16, fp32 acc.
// This revision: NO inline asm (tr16 -> scalar LDS reads; fences -> compiler).
// ---------------------------------------------------------------------------

typedef short  s16x4 __attribute__((ext_vector_type(4)));
typedef short  s16x8 __attribute__((ext_vector_type(8)));
typedef float  f32x4 __attribute__((ext_vector_type(4)));

#define MFMA32(a, b, c) __builtin_amdgcn_mfma_f32_16x16x32_bf16((a), (b), (c), 0, 0, 0)

// LDS layout (bytes)
constexpr int OFF_W1BHI = 0;        // [4 s][8 t][64 lane][8 e] bf16 = 32768
constexpr int OFF_W1BLO = 32768;    // 32768
constexpr int OFF_W0BHI = 65536;    // [8 t][64 lane][4 e] bf16 = 4096
constexpr int OFF_W0BLO = 69632;    // 4096
constexpr int OFF_B0    = 73728;    // 128 f32
constexpr int OFF_B1    = 74240;    // 128 f32
constexpr int OFF_W2    = 74752;    // 128 f32
constexpr int OFF_WAVE0 = 75264;
constexpr int WAVE_BYTES = 8320;    // per-wave scratch
//   per-wave: A32 [2][16][16] f32 @0 (2048)
//             Z0THI [2][256] bf16 @2048 (1024) ; Z0TLO @3072 (1024)
//             ZTHI  [2][2][256] bf16 @4096 (2048) ; ZTLO @6144 (2048)
//               (phase0 aliases: RAW f32[2][192] @4096, XTHI @+1536, XTLO @+2560)
//             SVEC [2][16] f32 @8192 (128)
constexpr int PW_A32   = 0;
constexpr int PW_Z0THI = 2048;
constexpr int PW_Z0TLO = 3072;
constexpr int PW_ZT    = 4096;
constexpr int PW_ZTHI  = 4096;
constexpr int PW_ZTLO  = 6144;
constexpr int PW_SVEC  = 8192;
constexpr int SMEM_TOTAL = OFF_WAVE0 + 8 * WAVE_BYTES;  // 141824
static_assert(SMEM_TOTAL == 141824, "lds size");

__device__ __forceinline__ unsigned short bf16_rn(float f) {
  unsigned u = __float_as_uint(f);
  u = u + 0x7FFFu + ((u >> 16) & 1u);
  return (unsigned short)(u >> 16);
}
__device__ __forceinline__ void split2(float f, unsigned short& h, unsigned short& l) {
  h = bf16_rn(f);
  float fh = __uint_as_float(((unsigned)h) << 16);
  l = bf16_rn(f - fh);
}
__device__ __forceinline__ s16x8 cat8(s16x4 a, s16x4 b) {
  return __builtin_shufflevector(a, b, 0, 1, 2, 3, 4, 5, 6, 7);
}

extern "C" __global__ void __launch_bounds__(512, 2)
gcnn_critic_kernel(const float* __restrict__ obs, const float* __restrict__ act,
                   const float* __restrict__ w0a, const float* __restrict__ b0a,
                   const float* __restrict__ w1a, const float* __restrict__ b1a,
                   const float* __restrict__ w2a, const float* __restrict__ b2a,
                   const float* __restrict__ w0b, const float* __restrict__ b0b,
                   const float* __restrict__ w1b, const float* __restrict__ b1b,
                   const float* __restrict__ w2b, const float* __restrict__ b2b,
                   float* __restrict__ out) {
  extern __shared__ char smem[];
  const int tid  = threadIdx.x;
  const int lane = tid & 63;
  const int wv   = tid >> 6;
  const int l15  = lane & 15;
  const int lg   = lane >> 4;
  const int bb   = blockIdx.x * 16 + wv * 2;  // first batch of this wave

  char* wbase = smem + OFF_WAVE0 + wv * WAVE_BYTES;
  float*          A32   = (float*)(wbase + PW_A32);
  unsigned short* Z0THI = (unsigned short*)(wbase + PW_Z0THI);
  unsigned short* Z0TLO = (unsigned short*)(wbase + PW_Z0TLO);
  unsigned short* ZTHI  = (unsigned short*)(wbase + PW_ZTHI);
  unsigned short* ZTLO  = (unsigned short*)(wbase + PW_ZTLO);
  float*          SVEC  = (float*)(wbase + PW_SVEC);
  float*          RAW   = (float*)(wbase + PW_ZT);             // phase-0 alias
  unsigned short* XTHI  = (unsigned short*)(wbase + PW_ZT + 1536);
  unsigned short* XTLO  = (unsigned short*)(wbase + PW_ZT + 2560);

  unsigned short* W1BHI = (unsigned short*)(smem + OFF_W1BHI);
  unsigned short* W1BLO = (unsigned short*)(smem + OFF_W1BLO);
  unsigned short* W0BHI = (unsigned short*)(smem + OFF_W0BHI);
  unsigned short* W0BLO = (unsigned short*)(smem + OFF_W0BLO);
  float* B0L = (float*)(smem + OFF_B0);
  float* B1L = (float*)(smem + OFF_B1);
  float* W2L = (float*)(smem + OFF_W2);

  // ------------------------- phase 0: batch setup -------------------------
  // stage raw features: [bi][0..159]=obs row, [160..191]=action row
#pragma unroll
  for (int i = 0; i < 6; ++i) {
    int idx = i * 64 + lane;             // 0..383
    int bi = (idx >= 192) ? 1 : 0;
    int j = idx - bi * 192;
    float v = (j < 160) ? obs[(bb + bi) * 160 + j] : act[(bb + bi) * 32 + (j - 160)];
    RAW[bi * 192 + j] = v;
  }
  __syncthreads();

  // xT[feat][src] (feat 10..15 zero-padded), split into hi/lo bf16
#pragma unroll
  for (int i = 0; i < 8; ++i) {
    int e = lane * 8 + i;                // 0..511
    int bi = e >> 8, rem = e & 255, f = rem >> 4, s = rem & 15;
    float v = 0.f;
    if (f < 8)        v = RAW[bi * 192 + s * 10 + 2 + f];
    else if (f < 10)  v = RAW[bi * 192 + 160 + s * 2 + (f - 8)];
    unsigned short h, l; split2(v, h, l);
    XTHI[bi * 256 + f * 16 + s] = h;
    XTLO[bi * 256 + f * 16 + s] = l;
  }
  // edge weights w[d][s] = exp(-||loc_d - loc_s||)
  float wreg[2][4];
#pragma unroll
  for (int bi = 0; bi < 2; ++bi)
#pragma unroll
    for (int i = 0; i < 4; ++i) {
      int p = lane * 4 + i, d = p >> 4, s = p & 15;
      float dx = RAW[bi * 192 + d * 10]     - RAW[bi * 192 + s * 10];
      float dy = RAW[bi * 192 + d * 10 + 1] - RAW[bi * 192 + s * 10 + 1];
      float w = expf(-sqrtf(dx * dx + dy * dy));
      wreg[bi][i] = w;
      A32[bi * 256 + d * 16 + s] = w;
    }
  __syncthreads();
  // deg / dinv  (deg > 0 always: self-edge weight = 1)
  if (lane < 32) {
    int bi = lane >> 4;
    float deg = 0.f;
#pragma unroll
    for (int s = 0; s < 16; ++s) deg += A32[bi * 256 + l15 * 16 + s];
    SVEC[bi * 16 + l15] = 1.0f / sqrtf(deg);
  }
  __syncthreads();
  // A[d][s] = dinv[s] * w * dinv[d]
#pragma unroll
  for (int bi = 0; bi < 2; ++bi)
#pragma unroll
    for (int i = 0; i < 4; ++i) {
      int p = lane * 4 + i, d = p >> 4, s = p & 15;
      A32[bi * 256 + d * 16 + s] = wreg[bi][i] * SVEC[bi * 16 + s] * SVEC[bi * 16 + d];
    }
  __syncthreads();

  // A-operand fragments: [Ahi | Alo], row = l15 (dst), k = 4*lg+e (src)
  s16x8 Aop[2];
#pragma unroll
  for (int bi = 0; bi < 2; ++bi) {
    const f32x4 a4 = *(const f32x4*)&A32[bi * 256 + l15 * 16 + lg * 4];
    unsigned short h[4], l[4];
#pragma unroll
    for (int r = 0; r < 4; ++r) split2(a4[r], h[r], l[r]);
    Aop[bi] = (s16x8){(short)h[0], (short)h[1], (short)h[2], (short)h[3],
                      (short)l[0], (short)l[1], (short)l[2], (short)l[3]};
  }

  // z0 = A@x  (split: Ahi*(xhi+xlo) + Alo*xhi), then write z0T[feat][dst]
  const s16x4 zero4 = {0, 0, 0, 0};
#pragma unroll
  for (int bi = 0; bi < 2; ++bi) {
    s16x4 xh = *(const s16x4*)&XTHI[bi * 256 + l15 * 16 + lg * 4];
    s16x4 xl = *(const s16x4*)&XTLO[bi * 256 + l15 * 16 + lg * 4];
    f32x4 zacc = {0.f, 0.f, 0.f, 0.f};
    zacc = MFMA32(Aop[bi], cat8(xh, xh), zacc);
    zacc = MFMA32(Aop[bi], cat8(xl, zero4), zacc);
    unsigned short h[4], l[4];
#pragma unroll
    for (int r = 0; r < 4; ++r) split2(zacc[r], h[r], l[r]);
    *(s16x4*)&Z0THI[bi * 256 + l15 * 16 + lg * 4] =
        (s16x4){(short)h[0], (short)h[1], (short)h[2], (short)h[3]};
    *(s16x4*)&Z0TLO[bi * 256 + l15 * 16 + lg * 4] =
        (s16x4){(short)l[0], (short)l[1], (short)l[2], (short)l[3]};
  }
  __syncthreads();
  // z0 as A-operand: elem j = z0[d=l15][k=4lg+j] (hi), elem 4+j = lo
  s16x8 z0op[2];
#pragma unroll
  for (int bi = 0; bi < 2; ++bi) {
    s16x8 v;
#pragma unroll
    for (int j = 0; j < 4; ++j) {
      int idx = bi * 256 + (lg * 4 + j) * 16 + l15;
      v[j]     = (short)Z0THI[idx];
      v[4 + j] = (short)Z0TLO[idx];
    }
    z0op[bi] = v;
  }

  float b2v0 = b2a[0], b2v1 = b2b[0];

  // ------------------------------ Q phases ------------------------------
#pragma unroll 1
  for (int qsel = 0; qsel < 2; ++qsel) {
    const float* W0 = qsel ? w0b : w0a;
    const float* B0 = qsel ? b0b : b0a;
    const float* W1 = qsel ? w1b : w1a;
    const float* B1 = qsel ? b1b : b1a;
    const float* W2 = qsel ? w2b : w2a;
    const float b2v = qsel ? b2v1 : b2v0;

    __syncthreads();  // previous phase done reading weight LDS
    for (int i = tid; i < 2048; i += 512) { W0BHI[i] = 0; W0BLO[i] = 0; }
    __syncthreads();
    // W0 fragments (K padded 10->16)
    for (int i = tid; i < 1280; i += 512) {
      int k = i >> 7, c = i & 127;
      int g = k >> 2, e = k & 3;
      int addr = ((c >> 4) * 64 + ((g << 4) | (c & 15))) * 4 + e;
      unsigned short h, l; split2(W0[i], h, l);
      W0BHI[addr] = h; W0BLO[addr] = l;
    }
    // W1 fragments: B[k][c] -> slot[s=k/32][t=c/16][lane=(g<<4)|(c&15)][e]
#pragma unroll
    for (int i = 0; i < 8; ++i) {
      int base = i * 2048 + tid * 4;
      float4 w4 = *(const float4*)&W1[base];
#pragma unroll
      for (int m = 0; m < 4; ++m) {
        int idx = base + m, k = idx >> 7, c = idx & 127;
        int s = k >> 5, kk = k & 31, rem = kk & 15;
        int e = (rem & 3) + ((kk >> 4) << 2);
        int ln = ((rem >> 2) << 4) | (c & 15);
        int addr = ((s * 8 + (c >> 4)) * 64 + ln) * 8 + e;
        float v = (m == 0) ? w4.x : (m == 1) ? w4.y : (m == 2) ? w4.z : w4.w;
        unsigned short h, l; split2(v, h, l);
        W1BHI[addr] = h; W1BLO[addr] = l;
      }
    }
    for (int i = tid; i < 128; i += 512) { B0L[i] = B0[i]; B1L[i] = B1[i]; W2L[i] = W2[i]; }
    __syncthreads();

    // ---- layer 1: h1 = relu(z0 @ W0 + b0) ----
    f32x4 h1[2][8];
#pragma unroll
    for (int t = 0; t < 8; ++t) {
      s16x4 wh = *(const s16x4*)&W0BHI[(t * 64 + lane) * 4];
      s16x4 wl = *(const s16x4*)&W0BLO[(t * 64 + lane) * 4];
      s16x8 Bh = cat8(wh, wh);
      s16x8 Bl = cat8(wl, zero4);
      float bv = B0L[t * 16 + l15];
#pragma unroll
      for (int bi = 0; bi < 2; ++bi) {
        f32x4 a = {0.f, 0.f, 0.f, 0.f};
        a = MFMA32(z0op[bi], Bh, a);
        a = MFMA32(z0op[bi], Bl, a);
#pragma unroll
        for (int r = 0; r < 4; ++r) a[r] = fmaxf(a[r] + bv, 0.f);
        h1[bi][t] = a;
      }
    }

    // ---- layer 2: h2 = relu((A@h1) @ W1 + b1), K processed in 32-chunks ----
    f32x4 acc2[2][8];
#pragma unroll
    for (int bi = 0; bi < 2; ++bi)
#pragma unroll
      for (int t = 0; t < 8; ++t) acc2[bi][t] = (f32x4){0.f, 0.f, 0.f, 0.f};

#pragma unroll 1
    for (int q = 0; q < 4; ++q) {
      // mix tiles 2q, 2q+1:  z1 = A@h1 (split), write zT[ch][dst] hi/lo
#pragma unroll
      for (int ti = 0; ti < 2; ++ti) {
        int t = 2 * q + ti;
#pragma unroll
        for (int bi = 0; bi < 2; ++bi) {
          unsigned short hh[4], hl[4];
#pragma unroll
          for (int r = 0; r < 4; ++r) split2(h1[bi][t][r], hh[r], hl[r]);
          s16x4 bh4 = {(short)hh[0], (short)hh[1], (short)hh[2], (short)hh[3]};
          s16x4 bl4 = {(short)hl[0], (short)hl[1], (short)hl[2], (short)hl[3]};
          f32x4 z = {0.f, 0.f, 0.f, 0.f};
          z = MFMA32(Aop[bi], cat8(bh4, bh4), z);
          z = MFMA32(Aop[bi], cat8(bl4, zero4), z);
          unsigned short zh[4], zl[4];
#pragma unroll
          for (int r = 0; r < 4; ++r) split2(z[r], zh[r], zl[r]);
          *(s16x4*)&ZTHI[bi * 512 + ti * 256 + l15 * 16 + lg * 4] =
              (s16x4){(short)zh[0], (short)zh[1], (short)zh[2], (short)zh[3]};
          *(s16x4*)&ZTLO[bi * 512 + ti * 256 + l15 * 16 + lg * 4] =
              (s16x4){(short)zl[0], (short)zl[1], (short)zl[2], (short)zl[3]};
        }
      }
      // zT as A-operand for this K=32 chunk (scalar LDS reads, no tr16)
      s16x8 zh8[2], zl8[2];
#pragma unroll
      for (int bi = 0; bi < 2; ++bi) {
        s16x8 vh, vl;
#pragma unroll
        for (int j = 0; j < 4; ++j) {
          int i0 = bi * 512 +       (lg * 4 + j) * 16 + l15;  // kk = 4lg+j
          int i1 = bi * 512 + 256 + (lg * 4 + j) * 16 + l15;  // kk = 16+4lg+j
          vh[j] = (short)ZTHI[i0]; vh[4 + j] = (short)ZTHI[i1];
          vl[j] = (short)ZTLO[i0]; vl[4 + j] = (short)ZTLO[i1];
        }
        zh8[bi] = vh; zl8[bi] = vl;
      }
#pragma unroll
      for (int t = 0; t < 8; ++t) {
        s16x8 Wh = *(const s16x8*)&W1BHI[((q * 8 + t) * 64 + lane) * 8];
        s16x8 Wl = *(const s16x8*)&W1BLO[((q * 8 + t) * 64 + lane) * 8];
#pragma unroll
        for (int bi = 0; bi < 2; ++bi) {
          acc2[bi][t] = MFMA32(zh8[bi], Wh, acc2[bi][t]);
          acc2[bi][t] = MFMA32(zh8[bi], Wl, acc2[bi][t]);
          acc2[bi][t] = MFMA32(zl8[bi], Wh, acc2[bi][t]);
        }
      }
    }

    // ---- layer 3: s = h2 @ W2 (VALU reduce), q = A@s + b2 ----
    float part[2][4] = {{0.f, 0.f, 0.f, 0.f}, {0.f, 0.f, 0.f, 0.f}};
#pragma unroll
    for (int t = 0; t < 8; ++t) {
      float bv  = B1L[t * 16 + l15];
      float wv2 = W2L[t * 16 + l15];
#pragma unroll
      for (int bi = 0; bi < 2; ++bi)
#pragma unroll
        for (int r = 0; r < 4; ++r) {
          float h2 = fmaxf(acc2[bi][t][r] + bv, 0.f);
          part[bi][r] += h2 * wv2;
        }
    }
#pragma unroll
    for (int d = 1; d < 16; d <<= 1)
#pragma unroll
      for (int bi = 0; bi < 2; ++bi)
#pragma unroll
        for (int r = 0; r < 4; ++r)
          part[bi][r] += __shfl_xor(part[bi][r], d, 64);
    if (l15 == 0) {
#pragma unroll
      for (int bi = 0; bi < 2; ++bi)
        *(f32x4*)&SVEC[bi * 16 + lg * 4] =
            (f32x4){part[bi][0], part[bi][1], part[bi][2], part[bi][3]};
    }
    __syncthreads();
    if (lane < 32) {
      int bi = lane >> 4;
      float qv = b2v;
#pragma unroll
      for (int s = 0; s < 16; ++s)
        qv += A32[bi * 256 + l15 * 16 + s] * SVEC[bi * 16 + s];
      out[qsel * 65536 + (bb + bi) * 16 + l15] = qv;
    }
  }
}

extern "C" void kernel_launch(void* const* d_in, const int* in_sizes, int n_in,
                              void* d_out, int out_size, void* d_ws, size_t ws_size,
                              hipStream_t stream) {
  (void)in_sizes; (void)n_in; (void)out_size; (void)d_ws; (void)ws_size;
  // >64KB dynamic LDS opt-in (idempotent; not a stream op, graph-capture safe)
  (void)hipFuncSetAttribute(reinterpret_cast<const void*>(gcnn_critic_kernel),
                            hipFuncAttributeMaxDynamicSharedMemorySize, SMEM_TOTAL);
  gcnn_critic_kernel<<<256, 512, SMEM_TOTAL, stream>>>(
      (const float*)d_in[0],  (const float*)d_in[1],
      (const float*)d_in[2],  (const float*)d_in[3],  (const float*)d_in[4],
      (const float*)d_in[5],  (const float*)d_in[6],  (const float*)d_in[7],
      (const float*)d_in[8],  (const float*)d_in[9],  (const float*)d_in[10],
      (const float*)d_in[11], (const float*)d_in[12], (const float*)d_in[13],
      (float*)d_out);
}

// Round 3
// 122.001 us; speedup vs baseline: 1.1561x; 1.1561x over previous
//
#include <hip/hip_runtime.h>

// ---------------------------------------------------------------------------
// GCNN Double-Q critic, MI355X (gfx950) — round 3.
// A is symmetric => compute all mixes as h^T @ A; the MFMA D-fragment of
// (h^T @ A) is exactly the A-fragment of the next GEMM (row=l15, k=4lg+r),
// so no transposes and no LDS in the Q pipeline. Weights are pre-split into
// hi/lo bf16 MFMA B-fragments by a prep kernel into d_ws (L2-resident).
// Split-precision bf16 (3-term) throughout; fp32 accum.
// ---------------------------------------------------------------------------

typedef short s16x4 __attribute__((ext_vector_type(4)));
typedef short s16x8 __attribute__((ext_vector_type(8)));
typedef float f32x4 __attribute__((ext_vector_type(4)));

#define MFMA32(a, b, c) __builtin_amdgcn_mfma_f32_16x16x32_bf16((a), (b), (c), 0, 0, 0)

// d_ws layout (units: shorts)
constexpr int WS_W0F = 0;       // [net][t=8][lane=64][8] : {h0..h3,l0..l3}
constexpr int WS_W1H = 8192;    // [net][q=4][t=8][lane=64][8] hi
constexpr int WS_W1L = 40960;   // same, lo
// total 73728 shorts = 144 KB

__device__ __forceinline__ unsigned short bf16_rn(float f) {
  unsigned u = __float_as_uint(f);
  u = u + 0x7FFFu + ((u >> 16) & 1u);
  return (unsigned short)(u >> 16);
}
__device__ __forceinline__ void split2(float f, unsigned short& h, unsigned short& l) {
  h = bf16_rn(f);
  float fh = __uint_as_float(((unsigned)h) << 16);
  l = bf16_rn(f - fh);
}
__device__ __forceinline__ s16x8 cat8(s16x4 a, s16x4 b) {
  return __builtin_shufflevector(a, b, 0, 1, 2, 3, 4, 5, 6, 7);
}

// ---------------------------- prep kernel ----------------------------------
extern "C" __global__ void __launch_bounds__(256)
prep_weights(const float* __restrict__ w0a, const float* __restrict__ w1a,
             const float* __restrict__ w0b, const float* __restrict__ w1b,
             unsigned short* __restrict__ ws) {
  const int tid = threadIdx.x;
  if (blockIdx.x < 16) {
    // W1 fragments: one 8-elem frag per thread. f = (net,q,t,lane)
    int f = blockIdx.x * 256 + tid;          // 0..4095
    int lane = f & 63, t = (f >> 6) & 7, q = (f >> 9) & 3, net = f >> 11;
    const float* W1 = net ? w1b : w1a;
    int c = 16 * t + (lane & 15);
    int kbase = 32 * q + 4 * (lane >> 4);
    s16x8 vh, vl;
#pragma unroll
    for (int e = 0; e < 8; ++e) {
      int k = kbase + (e & 3) + 16 * (e >> 2);
      unsigned short h, l; split2(W1[k * 128 + c], h, l);
      vh[e] = (short)h; vl[e] = (short)l;
    }
    int base = ((net * 4 + q) * 8 + t) * 64 + lane;
    ((s16x8*)(ws + WS_W1H))[base] = vh;
    ((s16x8*)(ws + WS_W1L))[base] = vl;
  } else {
    // W0 fragments (K padded 10->16 with zeros): 1024 frags, 4 per thread
#pragma unroll
    for (int i = 0; i < 4; ++i) {
      int f = i * 256 + tid;                 // 0..1023
      int lane = f & 63, t = (f >> 6) & 7, net = (f >> 9) & 1;
      const float* W0 = net ? w0b : w0a;
      int c = 16 * t + (lane & 15);
      int kbase = 4 * (lane >> 4);
      s16x8 v;
#pragma unroll
      for (int j = 0; j < 4; ++j) {
        int k = kbase + j;
        float w = (k < 10) ? W0[k * 128 + c] : 0.f;
        unsigned short h, l; split2(w, h, l);
        v[j] = (short)h; v[4 + j] = (short)l;
      }
      ((s16x8*)(ws + WS_W0F))[(net * 8 + t) * 64 + lane] = v;
    }
  }
}

// ---------------------------- main kernel ----------------------------------
extern "C" __global__ void __launch_bounds__(256, 4)
gcnn_critic_kernel(const float* __restrict__ obs, const float* __restrict__ act,
                   const float* __restrict__ b0a, const float* __restrict__ b1a,
                   const float* __restrict__ w2a, const float* __restrict__ b2a,
                   const float* __restrict__ b0b, const float* __restrict__ b1b,
                   const float* __restrict__ w2b, const float* __restrict__ b2b,
                   const unsigned short* __restrict__ ws,
                   float* __restrict__ out) {
  __shared__ float RAW[4][200];  // per-wave raw features (192 used)
  const int tid  = threadIdx.x;
  const int lane = tid & 63;
  const int wv   = tid >> 6;
  const int l15  = lane & 15;
  const int lg   = lane >> 4;
  const int batch = blockIdx.x * 4 + wv;  // one batch per wave

  float* raw = RAW[wv];

  // stage raw features: [0..159]=obs row, [160..191]=action row
#pragma unroll
  for (int i = 0; i < 3; ++i) {
    int j = i * 64 + lane;
    if (j < 192) {
      float v = (j < 160) ? obs[batch * 160 + j] : act[batch * 32 + (j - 160)];
      raw[j] = v;
    }
  }
  __syncthreads();

  // --- adjacency (per-lane): Af[j] = A[d=l15][s=4lg+j] ; symmetric ---
  float wreg[4];
  float wsum = 0.f;
#pragma unroll
  for (int j = 0; j < 4; ++j) {
    int s = 4 * lg + j;
    float dx = raw[l15 * 10]     - raw[s * 10];
    float dy = raw[l15 * 10 + 1] - raw[s * 10 + 1];
    float w = expf(-sqrtf(dx * dx + dy * dy));
    wreg[j] = w;
    wsum += w;
  }
  wsum += __shfl_xor(wsum, 16, 64);
  wsum += __shfl_xor(wsum, 32, 64);          // deg[d=l15], all lanes
  float dv = 1.0f / sqrtf(wsum);             // deg >= 1 (self loop)
  float Af[4];
  unsigned short Ah[4], Al[4];
#pragma unroll
  for (int j = 0; j < 4; ++j) {
    float dvs = __shfl(dv, 4 * lg + j, 64);  // dinv[s]
    Af[j] = wreg[j] * dv * dvs;
    split2(Af[j], Ah[j], Al[j]);
  }
  // A as B-operand fragments (symmetric => same values)
  const s16x8 ABh = {(short)Ah[0], (short)Ah[1], (short)Ah[2], (short)Ah[3],
                     (short)Ah[0], (short)Ah[1], (short)Ah[2], (short)Ah[3]};
  const s16x8 ABl = {(short)Al[0], (short)Al[1], (short)Al[2], (short)Al[3],
                     0, 0, 0, 0};

  // --- x^T A-fragment: x[src=4lg+j][feat=l15], split hi/lo ---
  s16x8 xop;
#pragma unroll
  for (int j = 0; j < 4; ++j) {
    int s = 4 * lg + j;
    float v = 0.f;
    if (l15 < 8)       v = raw[s * 10 + 2 + l15];
    else if (l15 < 10) v = raw[160 + s * 2 + (l15 - 8)];
    unsigned short h, l; split2(v, h, l);
    xop[j] = (short)h; xop[4 + j] = (short)l;
  }

  // --- z0^T = x^T @ A : D-frag == A-frag of layer 1 ---
  f32x4 z0 = {0.f, 0.f, 0.f, 0.f};
  z0 = MFMA32(xop, ABh, z0);   // xh*Ah + xl*Ah
  z0 = MFMA32(xop, ABl, z0);   // xh*Al
  s16x8 z0op;
#pragma unroll
  for (int r = 0; r < 4; ++r) {
    unsigned short h, l; split2(z0[r], h, l);
    z0op[r] = (short)h; z0op[4 + r] = (short)l;
  }

  const s16x8* W0F = (const s16x8*)(ws + WS_W0F);
  const s16x8* W1H = (const s16x8*)(ws + WS_W1H);
  const s16x8* W1L = (const s16x8*)(ws + WS_W1L);
  const s16x8 zero8 = {0, 0, 0, 0, 0, 0, 0, 0};

#pragma unroll 1
  for (int qsel = 0; qsel < 2; ++qsel) {
    const float* B0 = qsel ? b0b : b0a;
    const float* B1 = qsel ? b1b : b1a;
    const float* W2 = qsel ? w2b : w2a;
    const float b2v = qsel ? b2b[0] : b2a[0];
    const int net = qsel;

    // ---- layer 1: h1 = relu(z0@W0 + b0); D-frag -> mix A-frag, split ----
    s16x8 h1op[8];
#pragma unroll
    for (int t = 0; t < 8; ++t) {
      s16x8 wf = W0F[(net * 8 + t) * 64 + lane];
      s16x8 Bh = __builtin_shufflevector(wf, wf, 0, 1, 2, 3, 0, 1, 2, 3);
      s16x8 Bl = __builtin_shufflevector(wf, zero8, 4, 5, 6, 7, 8, 9, 10, 11);
      float bv = B0[16 * t + l15];
      f32x4 a = {0.f, 0.f, 0.f, 0.f};
      a = MFMA32(z0op, Bh, a);
      a = MFMA32(z0op, Bl, a);
#pragma unroll
      for (int r = 0; r < 4; ++r) {
        float h1 = fmaxf(a[r] + bv, 0.f);
        unsigned short h, l; split2(h1, h, l);
        h1op[t][r] = (short)h; h1op[t][4 + r] = (short)l;
      }
    }

    // ---- mix: z1^T_t = h1_t^T @ A ; D-frag -> layer-2 A-frag, split ----
    s16x4 zh4[8], zl4[8];
#pragma unroll
    for (int t = 0; t < 8; ++t) {
      f32x4 z = {0.f, 0.f, 0.f, 0.f};
      z = MFMA32(h1op[t], ABh, z);
      z = MFMA32(h1op[t], ABl, z);
#pragma unroll
      for (int r = 0; r < 4; ++r) {
        unsigned short h, l; split2(z[r], h, l);
        zh4[t][r] = (short)h; zl4[t][r] = (short)l;
      }
    }

    // ---- layer 2: h2 = relu(z1@W1 + b1), K in 32-chunks ----
    f32x4 acc[8];
#pragma unroll
    for (int t = 0; t < 8; ++t) acc[t] = (f32x4){0.f, 0.f, 0.f, 0.f};
#pragma unroll
    for (int q = 0; q < 4; ++q) {
      s16x8 zh8 = cat8(zh4[2 * q], zh4[2 * q + 1]);
      s16x8 zl8 = cat8(zl4[2 * q], zl4[2 * q + 1]);
      int base = ((net * 4 + q) * 8) * 64 + lane;
#pragma unroll
      for (int t = 0; t < 8; ++t) {
        s16x8 Wh = W1H[base + t * 64];
        s16x8 Wl = W1L[base + t * 64];
        acc[t] = MFMA32(zh8, Wh, acc[t]);
        acc[t] = MFMA32(zh8, Wl, acc[t]);
        acc[t] = MFMA32(zl8, Wh, acc[t]);
      }
    }

    // ---- layer 3: s[node] = sum_c relu(h2+b1)*W2 ; q = A@s + b2 ----
    float part[4] = {0.f, 0.f, 0.f, 0.f};
#pragma unroll
    for (int t = 0; t < 8; ++t) {
      float bv  = B1[16 * t + l15];
      float wv2 = W2[16 * t + l15];
#pragma unroll
      for (int r = 0; r < 4; ++r)
        part[r] += fmaxf(acc[t][r] + bv, 0.f) * wv2;
    }
#pragma unroll
    for (int d = 1; d < 16; d <<= 1)
#pragma unroll
      for (int r = 0; r < 4; ++r)
        part[r] += __shfl_xor(part[r], d, 64);
    // part[j] = s[node=4lg+j] (all l15). q[d=l15] = sum_s A[l15][s]*s[s]
    float pq = Af[0] * part[0] + Af[1] * part[1] + Af[2] * part[2] + Af[3] * part[3];
    pq += __shfl_xor(pq, 16, 64);
    pq += __shfl_xor(pq, 32, 64);
    if (lane < 16)
      out[qsel * 65536 + batch * 16 + l15] = pq + b2v;
  }
}

extern "C" void kernel_launch(void* const* d_in, const int* in_sizes, int n_in,
                              void* d_out, int out_size, void* d_ws, size_t ws_size,
                              hipStream_t stream) {
  (void)in_sizes; (void)n_in; (void)out_size; (void)ws_size;
  const float* obs = (const float*)d_in[0];
  const float* act = (const float*)d_in[1];
  const float* w0a = (const float*)d_in[2];
  const float* b0a = (const float*)d_in[3];
  const float* w1a = (const float*)d_in[4];
  const float* b1a = (const float*)d_in[5];
  const float* w2a = (const float*)d_in[6];
  const float* b2a = (const float*)d_in[7];
  const float* w0b = (const float*)d_in[8];
  const float* b0b = (const float*)d_in[9];
  const float* w1b = (const float*)d_in[10];
  const float* b1b = (const float*)d_in[11];
  const float* w2b = (const float*)d_in[12];
  const float* b2b = (const float*)d_in[13];
  unsigned short* ws = (unsigned short*)d_ws;

  prep_weights<<<17, 256, 0, stream>>>(w0a, w1a, w0b, w1b, ws);
  gcnn_critic_kernel<<<1024, 256, 0, stream>>>(
      obs, act, b0a, b1a, w2a, b2a, b0b, b1b, w2b, b2b, ws, (float*)d_out);
}

// Round 4
// 115.966 us; speedup vs baseline: 1.2163x; 1.0520x over previous
//
#include <hip/hip_runtime.h>

// ---------------------------------------------------------------------------
// GCNN Double-Q critic, MI355X (gfx950) — round 4.
// Structure as round 3 (A symmetric => transpose-free MFMA chain, weights
// pre-split into hi/lo bf16 B-fragments in d_ws). This round:
//   * packed split: round-half-up hi + truncated-lo residual, built directly
//     into packed bf16x2 words via v_perm_b32 (~2.5x fewer VALU on splits)
//   * s_setprio(1) around the layer-2 MFMA cluster (T5)
// ---------------------------------------------------------------------------

typedef short    s16x8 __attribute__((ext_vector_type(8)));
typedef float    f32x4 __attribute__((ext_vector_type(4)));
typedef unsigned u32x4 __attribute__((ext_vector_type(4)));

#define MFMA32(a, b, c) __builtin_amdgcn_mfma_f32_16x16x32_bf16((a), (b), (c), 0, 0, 0)

// d_ws layout (units: shorts)
constexpr int WS_W0F = 0;       // [net][t=8][lane=64][8] : {h0..h3,l0..l3}
constexpr int WS_W1H = 8192;    // [net][q=4][t=8][lane=64][8] hi
constexpr int WS_W1L = 40960;   // same, lo

__device__ __forceinline__ unsigned short bf16_rn(float f) {
  unsigned u = __float_as_uint(f);
  u = u + 0x7FFFu + ((u >> 16) & 1u);
  return (unsigned short)(u >> 16);
}
__device__ __forceinline__ void split2(float f, unsigned short& h, unsigned short& l) {
  h = bf16_rn(f);
  float fh = __uint_as_float(((unsigned)h) << 16);
  l = bf16_rn(f - fh);
}
// Packed split of a pair: H = {bf16_rhu(f1), bf16_rhu(f0)}, L = truncated
// residuals. 8 VALU per pair (add/add/perm/and/and/sub/sub/perm).
__device__ __forceinline__ void split_pk(float f0, float f1,
                                         unsigned& H, unsigned& L) {
  unsigned u0 = __float_as_uint(f0) + 0x8000u;
  unsigned u1 = __float_as_uint(f1) + 0x8000u;
  H = __builtin_amdgcn_perm(u1, u0, 0x07060302u);
  float r0 = f0 - __uint_as_float(u0 & 0xFFFF0000u);
  float r1 = f1 - __uint_as_float(u1 & 0xFFFF0000u);
  L = __builtin_amdgcn_perm(__float_as_uint(r1), __float_as_uint(r0), 0x07060302u);
}
__device__ __forceinline__ s16x8 as_s16x8(u32x4 v) {
  return __builtin_bit_cast(s16x8, v);
}

// ---------------------------- prep kernel ----------------------------------
extern "C" __global__ void __launch_bounds__(256)
prep_weights(const float* __restrict__ w0a, const float* __restrict__ w1a,
             const float* __restrict__ w0b, const float* __restrict__ w1b,
             unsigned short* __restrict__ ws) {
  const int tid = threadIdx.x;
  if (blockIdx.x < 16) {
    // W1 fragments: one 8-elem frag per thread. f = (net,q,t,lane)
    int f = blockIdx.x * 256 + tid;          // 0..4095
    int lane = f & 63, t = (f >> 6) & 7, q = (f >> 9) & 3, net = f >> 11;
    const float* W1 = net ? w1b : w1a;
    int c = 16 * t + (lane & 15);
    int kbase = 32 * q + 4 * (lane >> 4);
    s16x8 vh, vl;
#pragma unroll
    for (int e = 0; e < 8; ++e) {
      int k = kbase + (e & 3) + 16 * (e >> 2);
      unsigned short h, l; split2(W1[k * 128 + c], h, l);
      vh[e] = (short)h; vl[e] = (short)l;
    }
    int base = ((net * 4 + q) * 8 + t) * 64 + lane;
    ((s16x8*)(ws + WS_W1H))[base] = vh;
    ((s16x8*)(ws + WS_W1L))[base] = vl;
  } else {
    // W0 fragments (K padded 10->16 with zeros): 1024 frags, 4 per thread
#pragma unroll
    for (int i = 0; i < 4; ++i) {
      int f = i * 256 + tid;                 // 0..1023
      int lane = f & 63, t = (f >> 6) & 7, net = (f >> 9) & 1;
      const float* W0 = net ? w0b : w0a;
      int c = 16 * t + (lane & 15);
      int kbase = 4 * (lane >> 4);
      s16x8 v;
#pragma unroll
      for (int j = 0; j < 4; ++j) {
        int k = kbase + j;
        float w = (k < 10) ? W0[k * 128 + c] : 0.f;
        unsigned short h, l; split2(w, h, l);
        v[j] = (short)h; v[4 + j] = (short)l;
      }
      ((s16x8*)(ws + WS_W0F))[(net * 8 + t) * 64 + lane] = v;
    }
  }
}

// ---------------------------- main kernel ----------------------------------
extern "C" __global__ void __launch_bounds__(256, 4)
gcnn_critic_kernel(const float* __restrict__ obs, const float* __restrict__ act,
                   const float* __restrict__ b0a, const float* __restrict__ b1a,
                   const float* __restrict__ w2a, const float* __restrict__ b2a,
                   const float* __restrict__ b0b, const float* __restrict__ b1b,
                   const float* __restrict__ w2b, const float* __restrict__ b2b,
                   const unsigned short* __restrict__ ws,
                   float* __restrict__ out) {
  __shared__ float RAW[4][200];  // per-wave raw features (192 used)
  const int tid  = threadIdx.x;
  const int lane = tid & 63;
  const int wv   = tid >> 6;
  const int l15  = lane & 15;
  const int lg   = lane >> 4;
  const int batch = blockIdx.x * 4 + wv;  // one batch per wave

  float* raw = RAW[wv];

  // stage raw features: [0..159]=obs row, [160..191]=action row
#pragma unroll
  for (int i = 0; i < 3; ++i) {
    int j = i * 64 + lane;
    if (j < 192) {
      float v = (j < 160) ? obs[batch * 160 + j] : act[batch * 32 + (j - 160)];
      raw[j] = v;
    }
  }
  __syncthreads();

  // --- adjacency (per-lane): Af[j] = A[d=l15][s=4lg+j] ; symmetric ---
  float wreg[4];
  float wsum = 0.f;
#pragma unroll
  for (int j = 0; j < 4; ++j) {
    int s = 4 * lg + j;
    float dx = raw[l15 * 10]     - raw[s * 10];
    float dy = raw[l15 * 10 + 1] - raw[s * 10 + 1];
    float w = expf(-sqrtf(dx * dx + dy * dy));
    wreg[j] = w;
    wsum += w;
  }
  wsum += __shfl_xor(wsum, 16, 64);
  wsum += __shfl_xor(wsum, 32, 64);          // deg[d=l15], all lanes
  float dv = 1.0f / sqrtf(wsum);             // deg >= 1 (self loop)
  float Af[4];
#pragma unroll
  for (int j = 0; j < 4; ++j) {
    float dvs = __shfl(dv, 4 * lg + j, 64);  // dinv[s]
    Af[j] = wreg[j] * dv * dvs;
  }
  unsigned AH01, AL01, AH23, AL23;
  split_pk(Af[0], Af[1], AH01, AL01);
  split_pk(Af[2], Af[3], AH23, AL23);
  const s16x8 ABh = as_s16x8((u32x4){AH01, AH23, AH01, AH23});
  const s16x8 ABl = as_s16x8((u32x4){AL01, AL23, 0u, 0u});

  // --- x^T A-fragment: x[src=4lg+j][feat=l15], split hi/lo ---
  float xv[4];
#pragma unroll
  for (int j = 0; j < 4; ++j) {
    int s = 4 * lg + j;
    float v = 0.f;
    if (l15 < 8)       v = raw[s * 10 + 2 + l15];
    else if (l15 < 10) v = raw[160 + s * 2 + (l15 - 8)];
    xv[j] = v;
  }
  unsigned xH0, xL0, xH1, xL1;
  split_pk(xv[0], xv[1], xH0, xL0);
  split_pk(xv[2], xv[3], xH1, xL1);
  const s16x8 xop = as_s16x8((u32x4){xH0, xH1, xL0, xL1});

  // --- z0^T = x^T @ A : D-frag == A-frag of layer 1 ---
  f32x4 z0 = {0.f, 0.f, 0.f, 0.f};
  z0 = MFMA32(xop, ABh, z0);   // xh*Ah + xl*Ah
  z0 = MFMA32(xop, ABl, z0);   // xh*Al
  unsigned zH0, zL0, zH1, zL1;
  split_pk(z0[0], z0[1], zH0, zL0);
  split_pk(z0[2], z0[3], zH1, zL1);
  const s16x8 z0op = as_s16x8((u32x4){zH0, zH1, zL0, zL1});

  const s16x8* W0F = (const s16x8*)(ws + WS_W0F);
  const s16x8* W1H = (const s16x8*)(ws + WS_W1H);
  const s16x8* W1L = (const s16x8*)(ws + WS_W1L);
  const s16x8 zero8 = {0, 0, 0, 0, 0, 0, 0, 0};

#pragma unroll 1
  for (int qsel = 0; qsel < 2; ++qsel) {
    const float* B0 = qsel ? b0b : b0a;
    const float* B1 = qsel ? b1b : b1a;
    const float* W2 = qsel ? w2b : w2a;
    const float b2v = qsel ? b2b[0] : b2a[0];
    const int net = qsel;

    // ---- layer 1: h1 = relu(z0@W0 + b0); D-frag -> mix A-frag, packed ----
    s16x8 h1op[8];
#pragma unroll
    for (int t = 0; t < 8; ++t) {
      s16x8 wf = W0F[(net * 8 + t) * 64 + lane];
      s16x8 Bh = __builtin_shufflevector(wf, wf, 0, 1, 2, 3, 0, 1, 2, 3);
      s16x8 Bl = __builtin_shufflevector(wf, zero8, 4, 5, 6, 7, 8, 9, 10, 11);
      float bv = B0[16 * t + l15];
      f32x4 a = {0.f, 0.f, 0.f, 0.f};
      a = MFMA32(z0op, Bh, a);
      a = MFMA32(z0op, Bl, a);
      float a0 = fmaxf(a[0] + bv, 0.f), a1 = fmaxf(a[1] + bv, 0.f);
      float a2 = fmaxf(a[2] + bv, 0.f), a3 = fmaxf(a[3] + bv, 0.f);
      unsigned H0, L0, H1, L1;
      split_pk(a0, a1, H0, L0);
      split_pk(a2, a3, H1, L1);
      h1op[t] = as_s16x8((u32x4){H0, H1, L0, L1});
    }

    // ---- mix: z1^T_t = h1_t^T @ A ; D-frag -> layer-2 A-frag, packed ----
    unsigned zHw[8][2], zLw[8][2];
#pragma unroll
    for (int t = 0; t < 8; ++t) {
      f32x4 z = {0.f, 0.f, 0.f, 0.f};
      z = MFMA32(h1op[t], ABh, z);
      z = MFMA32(h1op[t], ABl, z);
      split_pk(z[0], z[1], zHw[t][0], zLw[t][0]);
      split_pk(z[2], z[3], zHw[t][1], zLw[t][1]);
    }

    // ---- layer 2: h2 = relu(z1@W1 + b1), K in 32-chunks ----
    f32x4 acc[8];
#pragma unroll
    for (int t = 0; t < 8; ++t) acc[t] = (f32x4){0.f, 0.f, 0.f, 0.f};
    __builtin_amdgcn_s_setprio(1);
#pragma unroll
    for (int q = 0; q < 4; ++q) {
      s16x8 zh8 = as_s16x8(
          (u32x4){zHw[2 * q][0], zHw[2 * q][1], zHw[2 * q + 1][0], zHw[2 * q + 1][1]});
      s16x8 zl8 = as_s16x8(
          (u32x4){zLw[2 * q][0], zLw[2 * q][1], zLw[2 * q + 1][0], zLw[2 * q + 1][1]});
      int base = ((net * 4 + q) * 8) * 64 + lane;
#pragma unroll
      for (int t = 0; t < 8; ++t) {
        s16x8 Wh = W1H[base + t * 64];
        s16x8 Wl = W1L[base + t * 64];
        acc[t] = MFMA32(zh8, Wh, acc[t]);
        acc[t] = MFMA32(zh8, Wl, acc[t]);
        acc[t] = MFMA32(zl8, Wh, acc[t]);
      }
    }
    __builtin_amdgcn_s_setprio(0);

    // ---- layer 3: s[node] = sum_c relu(h2+b1)*W2 ; q = A@s + b2 ----
    float part[4] = {0.f, 0.f, 0.f, 0.f};
#pragma unroll
    for (int t = 0; t < 8; ++t) {
      float bv  = B1[16 * t + l15];
      float wv2 = W2[16 * t + l15];
#pragma unroll
      for (int r = 0; r < 4; ++r)
        part[r] += fmaxf(acc[t][r] + bv, 0.f) * wv2;
    }
#pragma unroll
    for (int d = 1; d < 16; d <<= 1)
#pragma unroll
      for (int r = 0; r < 4; ++r)
        part[r] += __shfl_xor(part[r], d, 64);
    // part[j] = s[node=4lg+j] (all l15). q[d=l15] = sum_s A[l15][s]*s[s]
    float pq = Af[0] * part[0] + Af[1] * part[1] + Af[2] * part[2] + Af[3] * part[3];
    pq += __shfl_xor(pq, 16, 64);
    pq += __shfl_xor(pq, 32, 64);
    if (lane < 16)
      out[qsel * 65536 + batch * 16 + l15] = pq + b2v;
  }
}

extern "C" void kernel_launch(void* const* d_in, const int* in_sizes, int n_in,
                              void* d_out, int out_size, void* d_ws, size_t ws_size,
                              hipStream_t stream) {
  (void)in_sizes; (void)n_in; (void)out_size; (void)ws_size;
  const float* obs = (const float*)d_in[0];
  const float* act = (const float*)d_in[1];
  const float* w0a = (const float*)d_in[2];
  const float* b0a = (const float*)d_in[3];
  const float* w1a = (const float*)d_in[4];
  const float* b1a = (const float*)d_in[5];
  const float* w2a = (const float*)d_in[6];
  const float* b2a = (const float*)d_in[7];
  const float* w0b = (const float*)d_in[8];
  const float* b0b = (const float*)d_in[9];
  const float* w1b = (const float*)d_in[10];
  const float* b1b = (const float*)d_in[11];
  const float* w2b = (const float*)d_in[12];
  const float* b2b = (const float*)d_in[13];
  unsigned short* ws = (unsigned short*)d_ws;

  prep_weights<<<17, 256, 0, stream>>>(w0a, w1a, w0b, w1b, ws);
  gcnn_critic_kernel<<<1024, 256, 0, stream>>>(
      obs, act, b0a, b1a, w2a, b2a, b0b, b1b, w2b, b2b, ws, (float*)d_out);
}

// Round 7
// 108.486 us; speedup vs baseline: 1.3001x; 1.0689x over previous
//
#include <hip/hip_runtime.h>

// ---------------------------------------------------------------------------
// GCNN Double-Q critic, MI355X (gfx950) — round 5 (2nd resubmit: broker
// timeouts both attempts; kernel never executed).
// Structure: A symmetric => transpose-free MFMA chain (D-frag == next A-frag).
// Weights pre-split into hi/lo bf16 B-fragments in d_ws by prep kernel.
// This round: one net per block (grid 1024 = 512 batch-groups x 2 nets);
// the block's 64KB of W1 fragments staged once into LDS, shared by 8 waves.
// Weight L2 traffic drops 8x (512MB -> 64MB); hot loop reads LDS b128.
// ---------------------------------------------------------------------------

typedef short    s16x8 __attribute__((ext_vector_type(8)));
typedef float    f32x4 __attribute__((ext_vector_type(4)));
typedef unsigned u32x4 __attribute__((ext_vector_type(4)));

#define MFMA32(a, b, c) __builtin_amdgcn_mfma_f32_16x16x32_bf16((a), (b), (c), 0, 0, 0)

// d_ws layout (units: shorts)
constexpr int WS_W0F = 0;       // [net][t=8][lane=64][8] : {h0..h3,l0..l3}
constexpr int WS_W1H = 8192;    // [net][q=4][t=8][lane=64][8] hi
constexpr int WS_W1L = 40960;   // same, lo

// dynamic LDS: [0,32KB) W1H frags, [32KB,64KB) W1L frags, [64KB,+6.4KB) RAW
constexpr int LDS_RAW   = 65536;
constexpr int SMEM_TOTAL = 65536 + 8 * 200 * 4;  // 71936

__device__ __forceinline__ unsigned short bf16_rn(float f) {
  unsigned u = __float_as_uint(f);
  u = u + 0x7FFFu + ((u >> 16) & 1u);
  return (unsigned short)(u >> 16);
}
__device__ __forceinline__ void split2(float f, unsigned short& h, unsigned short& l) {
  h = bf16_rn(f);
  float fh = __uint_as_float(((unsigned)h) << 16);
  l = bf16_rn(f - fh);
}
// Packed split of a pair: H = {bf16_rhu(f1), bf16_rhu(f0)}, L = truncated
// residuals. 8 VALU per pair.
__device__ __forceinline__ void split_pk(float f0, float f1,
                                         unsigned& H, unsigned& L) {
  unsigned u0 = __float_as_uint(f0) + 0x8000u;
  unsigned u1 = __float_as_uint(f1) + 0x8000u;
  H = __builtin_amdgcn_perm(u1, u0, 0x07060302u);
  float r0 = f0 - __uint_as_float(u0 & 0xFFFF0000u);
  float r1 = f1 - __uint_as_float(u1 & 0xFFFF0000u);
  L = __builtin_amdgcn_perm(__float_as_uint(r1), __float_as_uint(r0), 0x07060302u);
}
__device__ __forceinline__ s16x8 as_s16x8(u32x4 v) {
  return __builtin_bit_cast(s16x8, v);
}

// ---------------------------- prep kernel ----------------------------------
extern "C" __global__ void __launch_bounds__(256)
prep_weights(const float* __restrict__ w0a, const float* __restrict__ w1a,
             const float* __restrict__ w0b, const float* __restrict__ w1b,
             unsigned short* __restrict__ ws) {
  const int tid = threadIdx.x;
  if (blockIdx.x < 16) {
    // W1 fragments: one 8-elem frag per thread. f = (net,q,t,lane)
    int f = blockIdx.x * 256 + tid;          // 0..4095
    int lane = f & 63, t = (f >> 6) & 7, q = (f >> 9) & 3, net = f >> 11;
    const float* W1 = net ? w1b : w1a;
    int c = 16 * t + (lane & 15);
    int kbase = 32 * q + 4 * (lane >> 4);
    s16x8 vh, vl;
#pragma unroll
    for (int e = 0; e < 8; ++e) {
      int k = kbase + (e & 3) + 16 * (e >> 2);
      unsigned short h, l; split2(W1[k * 128 + c], h, l);
      vh[e] = (short)h; vl[e] = (short)l;
    }
    int base = ((net * 4 + q) * 8 + t) * 64 + lane;
    ((s16x8*)(ws + WS_W1H))[base] = vh;
    ((s16x8*)(ws + WS_W1L))[base] = vl;
  } else {
    // W0 fragments (K padded 10->16 with zeros): 1024 frags, 4 per thread
#pragma unroll
    for (int i = 0; i < 4; ++i) {
      int f = i * 256 + tid;                 // 0..1023
      int lane = f & 63, t = (f >> 6) & 7, net = (f >> 9) & 1;
      const float* W0 = net ? w0b : w0a;
      int c = 16 * t + (lane & 15);
      int kbase = 4 * (lane >> 4);
      s16x8 v;
#pragma unroll
      for (int j = 0; j < 4; ++j) {
        int k = kbase + j;
        float w = (k < 10) ? W0[k * 128 + c] : 0.f;
        unsigned short h, l; split2(w, h, l);
        v[j] = (short)h; v[4 + j] = (short)l;
      }
      ((s16x8*)(ws + WS_W0F))[(net * 8 + t) * 64 + lane] = v;
    }
  }
}

// ---------------------------- main kernel ----------------------------------
extern "C" __global__ void __launch_bounds__(512, 4)
gcnn_critic_kernel(const float* __restrict__ obs, const float* __restrict__ act,
                   const float* __restrict__ b0a, const float* __restrict__ b1a,
                   const float* __restrict__ w2a, const float* __restrict__ b2a,
                   const float* __restrict__ b0b, const float* __restrict__ b1b,
                   const float* __restrict__ w2b, const float* __restrict__ b2b,
                   const unsigned short* __restrict__ ws,
                   float* __restrict__ out) {
  extern __shared__ char smem[];
  const int tid  = threadIdx.x;
  const int lane = tid & 63;
  const int wv   = tid >> 6;
  const int l15  = lane & 15;
  const int lg   = lane >> 4;
  const int net  = blockIdx.x & 1;
  const int batch = (blockIdx.x >> 1) * 8 + wv;  // one batch per wave

  s16x8* lH = (s16x8*)smem;                  // 2048 fragments (32KB)
  s16x8* lL = (s16x8*)(smem + 32768);        // 2048 fragments (32KB)
  float* raw = (float*)(smem + LDS_RAW) + wv * 200;

  // ---- cooperative stage: this net's W1 fragments into LDS (64KB) ----
  {
    const s16x8* gH = (const s16x8*)(ws + WS_W1H) + net * 2048;
    const s16x8* gL = (const s16x8*)(ws + WS_W1L) + net * 2048;
#pragma unroll
    for (int k = 0; k < 4; ++k) lH[tid + k * 512] = gH[tid + k * 512];
#pragma unroll
    for (int k = 0; k < 4; ++k) lL[tid + k * 512] = gL[tid + k * 512];
  }
  // stage raw features: [0..159]=obs row, [160..191]=action row
#pragma unroll
  for (int i = 0; i < 3; ++i) {
    int j = i * 64 + lane;
    if (j < 192) {
      float v = (j < 160) ? obs[batch * 160 + j] : act[batch * 32 + (j - 160)];
      raw[j] = v;
    }
  }
  __syncthreads();

  // --- adjacency (per-lane): Af[j] = A[d=l15][s=4lg+j] ; symmetric ---
  float wreg[4];
  float wsum = 0.f;
#pragma unroll
  for (int j = 0; j < 4; ++j) {
    int s = 4 * lg + j;
    float dx = raw[l15 * 10]     - raw[s * 10];
    float dy = raw[l15 * 10 + 1] - raw[s * 10 + 1];
    float w = expf(-sqrtf(dx * dx + dy * dy));
    wreg[j] = w;
    wsum += w;
  }
  wsum += __shfl_xor(wsum, 16, 64);
  wsum += __shfl_xor(wsum, 32, 64);          // deg[d=l15], all lanes
  float dv = 1.0f / sqrtf(wsum);             // deg >= 1 (self loop)
  float Af[4];
#pragma unroll
  for (int j = 0; j < 4; ++j) {
    float dvs = __shfl(dv, 4 * lg + j, 64);  // dinv[s]
    Af[j] = wreg[j] * dv * dvs;
  }
  unsigned AH01, AL01, AH23, AL23;
  split_pk(Af[0], Af[1], AH01, AL01);
  split_pk(Af[2], Af[3], AH23, AL23);
  const s16x8 ABh = as_s16x8((u32x4){AH01, AH23, AH01, AH23});
  const s16x8 ABl = as_s16x8((u32x4){AL01, AL23, 0u, 0u});

  // --- x^T A-fragment: x[src=4lg+j][feat=l15], split hi/lo ---
  float xv[4];
#pragma unroll
  for (int j = 0; j < 4; ++j) {
    int s = 4 * lg + j;
    float v = 0.f;
    if (l15 < 8)       v = raw[s * 10 + 2 + l15];
    else if (l15 < 10) v = raw[160 + s * 2 + (l15 - 8)];
    xv[j] = v;
  }
  unsigned xH0, xL0, xH1, xL1;
  split_pk(xv[0], xv[1], xH0, xL0);
  split_pk(xv[2], xv[3], xH1, xL1);
  const s16x8 xop = as_s16x8((u32x4){xH0, xH1, xL0, xL1});

  // --- z0^T = x^T @ A : D-frag == A-frag of layer 1 ---
  f32x4 z0 = {0.f, 0.f, 0.f, 0.f};
  z0 = MFMA32(xop, ABh, z0);   // xh*Ah + xl*Ah
  z0 = MFMA32(xop, ABl, z0);   // xh*Al
  unsigned zH0, zL0, zH1, zL1;
  split_pk(z0[0], z0[1], zH0, zL0);
  split_pk(z0[2], z0[3], zH1, zL1);
  const s16x8 z0op = as_s16x8((u32x4){zH0, zH1, zL0, zL1});

  const s16x8* W0F = (const s16x8*)(ws + WS_W0F);
  const float* B0 = net ? b0b : b0a;
  const float* B1 = net ? b1b : b1a;
  const float* W2 = net ? w2b : w2a;
  const float b2v = net ? b2b[0] : b2a[0];
  const s16x8 zero8 = {0, 0, 0, 0, 0, 0, 0, 0};

  // ---- layer 1: h1 = relu(z0@W0 + b0); D-frag -> mix A-frag, packed ----
  s16x8 h1op[8];
#pragma unroll
  for (int t = 0; t < 8; ++t) {
    s16x8 wf = W0F[(net * 8 + t) * 64 + lane];
    s16x8 Bh = __builtin_shufflevector(wf, wf, 0, 1, 2, 3, 0, 1, 2, 3);
    s16x8 Bl = __builtin_shufflevector(wf, zero8, 4, 5, 6, 7, 8, 9, 10, 11);
    float bv = B0[16 * t + l15];
    f32x4 a = {0.f, 0.f, 0.f, 0.f};
    a = MFMA32(z0op, Bh, a);
    a = MFMA32(z0op, Bl, a);
    float a0 = fmaxf(a[0] + bv, 0.f), a1 = fmaxf(a[1] + bv, 0.f);
    float a2 = fmaxf(a[2] + bv, 0.f), a3 = fmaxf(a[3] + bv, 0.f);
    unsigned H0, L0, H1, L1;
    split_pk(a0, a1, H0, L0);
    split_pk(a2, a3, H1, L1);
    h1op[t] = as_s16x8((u32x4){H0, H1, L0, L1});
  }

  // ---- mix: z1^T_t = h1_t^T @ A ; D-frag -> layer-2 A-frag, packed ----
  unsigned zHw[8][2], zLw[8][2];
#pragma unroll
  for (int t = 0; t < 8; ++t) {
    f32x4 z = {0.f, 0.f, 0.f, 0.f};
    z = MFMA32(h1op[t], ABh, z);
    z = MFMA32(h1op[t], ABl, z);
    split_pk(z[0], z[1], zHw[t][0], zLw[t][0]);
    split_pk(z[2], z[3], zHw[t][1], zLw[t][1]);
  }

  // ---- layer 2: h2 = relu(z1@W1 + b1), K in 32-chunks, W1 from LDS ----
  f32x4 acc[8];
#pragma unroll
  for (int t = 0; t < 8; ++t) acc[t] = (f32x4){0.f, 0.f, 0.f, 0.f};
  __builtin_amdgcn_s_setprio(1);
#pragma unroll
  for (int q = 0; q < 4; ++q) {
    s16x8 zh8 = as_s16x8(
        (u32x4){zHw[2 * q][0], zHw[2 * q][1], zHw[2 * q + 1][0], zHw[2 * q + 1][1]});
    s16x8 zl8 = as_s16x8(
        (u32x4){zLw[2 * q][0], zLw[2 * q][1], zLw[2 * q + 1][0], zLw[2 * q + 1][1]});
    int base = (q * 8) * 64 + lane;
#pragma unroll
    for (int t = 0; t < 8; ++t) {
      s16x8 Wh = lH[base + t * 64];
      s16x8 Wl = lL[base + t * 64];
      acc[t] = MFMA32(zh8, Wh, acc[t]);
      acc[t] = MFMA32(zh8, Wl, acc[t]);
      acc[t] = MFMA32(zl8, Wh, acc[t]);
    }
  }
  __builtin_amdgcn_s_setprio(0);

  // ---- layer 3: s[node] = sum_c relu(h2+b1)*W2 ; q = A@s + b2 ----
  float part[4] = {0.f, 0.f, 0.f, 0.f};
#pragma unroll
  for (int t = 0; t < 8; ++t) {
    float bv  = B1[16 * t + l15];
    float wv2 = W2[16 * t + l15];
#pragma unroll
    for (int r = 0; r < 4; ++r)
      part[r] += fmaxf(acc[t][r] + bv, 0.f) * wv2;
  }
#pragma unroll
  for (int d = 1; d < 16; d <<= 1)
#pragma unroll
    for (int r = 0; r < 4; ++r)
      part[r] += __shfl_xor(part[r], d, 64);
  // part[j] = s[node=4lg+j] (all l15). q[d=l15] = sum_s A[l15][s]*s[s]
  float pq = Af[0] * part[0] + Af[1] * part[1] + Af[2] * part[2] + Af[3] * part[3];
  pq += __shfl_xor(pq, 16, 64);
  pq += __shfl_xor(pq, 32, 64);
  if (lane < 16)
    out[net * 65536 + batch * 16 + l15] = pq + b2v;
}

extern "C" void kernel_launch(void* const* d_in, const int* in_sizes, int n_in,
                              void* d_out, int out_size, void* d_ws, size_t ws_size,
                              hipStream_t stream) {
  (void)in_sizes; (void)n_in; (void)out_size; (void)ws_size;
  const float* obs = (const float*)d_in[0];
  const float* act = (const float*)d_in[1];
  const float* w0a = (const float*)d_in[2];
  const float* b0a = (const float*)d_in[3];
  const float* w1a = (const float*)d_in[4];
  const float* b1a = (const float*)d_in[5];
  const float* w2a = (const float*)d_in[6];
  const float* b2a = (const float*)d_in[7];
  const float* w0b = (const float*)d_in[8];
  const float* b0b = (const float*)d_in[9];
  const float* w1b = (const float*)d_in[10];
  const float* b1b = (const float*)d_in[11];
  const float* w2b = (const float*)d_in[12];
  const float* b2b = (const float*)d_in[13];
  unsigned short* ws = (unsigned short*)d_ws;

  prep_weights<<<17, 256, 0, stream>>>(w0a, w1a, w0b, w1b, ws);
  gcnn_critic_kernel<<<1024, 512, SMEM_TOTAL, stream>>>(
      obs, act, b0a, b1a, w2a, b2a, b0b, b1b, w2b, b2b, ws, (float*)d_out);
}

// Round 8
// 103.182 us; speedup vs baseline: 1.3670x; 1.0514x over previous
//
#include <hip/hip_runtime.h>

// ---------------------------------------------------------------------------
// GCNN Double-Q critic, MI355X (gfx950) — round 8.
// Structure: A symmetric => transpose-free MFMA chain (D-frag == next A-frag).
// Round 8: layer-2 weights stored as SINGLE round-to-nearest bf16 (W1 frag),
// z kept split hi+lo => 2 MFMAs + 1 ds_read_b128 per (q,t) instead of 3+2.
// Layers 0/1/mix keep full 3-term split precision.
// ---------------------------------------------------------------------------

typedef short    s16x8 __attribute__((ext_vector_type(8)));
typedef float    f32x4 __attribute__((ext_vector_type(4)));
typedef unsigned u32x4 __attribute__((ext_vector_type(4)));

#define MFMA32(a, b, c) __builtin_amdgcn_mfma_f32_16x16x32_bf16((a), (b), (c), 0, 0, 0)

// d_ws layout (units: shorts)
constexpr int WS_W0F = 0;       // [net][t=8][lane=64][8] : {h0..h3,l0..l3}
constexpr int WS_W1  = 8192;    // [net][q=4][t=8][lane=64][8] bf16 RN

// dynamic LDS: [0,32KB) W1 frags (this net), [32KB,+6.4KB) RAW
constexpr int LDS_RAW    = 32768;
constexpr int SMEM_TOTAL = 32768 + 8 * 200 * 4;  // 39168

__device__ __forceinline__ unsigned short bf16_rn(float f) {
  unsigned u = __float_as_uint(f);
  u = u + 0x7FFFu + ((u >> 16) & 1u);
  return (unsigned short)(u >> 16);
}
__device__ __forceinline__ void split2(float f, unsigned short& h, unsigned short& l) {
  h = bf16_rn(f);
  float fh = __uint_as_float(((unsigned)h) << 16);
  l = bf16_rn(f - fh);
}
// Packed split of a pair: H = {bf16_rhu(f1), bf16_rhu(f0)}, L = truncated
// residuals. 8 VALU per pair.
__device__ __forceinline__ void split_pk(float f0, float f1,
                                         unsigned& H, unsigned& L) {
  unsigned u0 = __float_as_uint(f0) + 0x8000u;
  unsigned u1 = __float_as_uint(f1) + 0x8000u;
  H = __builtin_amdgcn_perm(u1, u0, 0x07060302u);
  float r0 = f0 - __uint_as_float(u0 & 0xFFFF0000u);
  float r1 = f1 - __uint_as_float(u1 & 0xFFFF0000u);
  L = __builtin_amdgcn_perm(__float_as_uint(r1), __float_as_uint(r0), 0x07060302u);
}
__device__ __forceinline__ s16x8 as_s16x8(u32x4 v) {
  return __builtin_bit_cast(s16x8, v);
}

// ---------------------------- prep kernel ----------------------------------
extern "C" __global__ void __launch_bounds__(256)
prep_weights(const float* __restrict__ w0a, const float* __restrict__ w1a,
             const float* __restrict__ w0b, const float* __restrict__ w1b,
             unsigned short* __restrict__ ws) {
  const int tid = threadIdx.x;
  if (blockIdx.x < 16) {
    // W1 fragments (single bf16 RN): one 8-elem frag per thread.
    int f = blockIdx.x * 256 + tid;          // 0..4095
    int lane = f & 63, t = (f >> 6) & 7, q = (f >> 9) & 3, net = f >> 11;
    const float* W1 = net ? w1b : w1a;
    int c = 16 * t + (lane & 15);
    int kbase = 32 * q + 4 * (lane >> 4);
    s16x8 v;
#pragma unroll
    for (int e = 0; e < 8; ++e) {
      int k = kbase + (e & 3) + 16 * (e >> 2);
      v[e] = (short)bf16_rn(W1[k * 128 + c]);
    }
    ((s16x8*)(ws + WS_W1))[((net * 4 + q) * 8 + t) * 64 + lane] = v;
  } else {
    // W0 fragments hi/lo (K padded 10->16 with zeros): 1024 frags, 4/thread
#pragma unroll
    for (int i = 0; i < 4; ++i) {
      int f = i * 256 + tid;                 // 0..1023
      int lane = f & 63, t = (f >> 6) & 7, net = (f >> 9) & 1;
      const float* W0 = net ? w0b : w0a;
      int c = 16 * t + (lane & 15);
      int kbase = 4 * (lane >> 4);
      s16x8 v;
#pragma unroll
      for (int j = 0; j < 4; ++j) {
        int k = kbase + j;
        float w = (k < 10) ? W0[k * 128 + c] : 0.f;
        unsigned short h, l; split2(w, h, l);
        v[j] = (short)h; v[4 + j] = (short)l;
      }
      ((s16x8*)(ws + WS_W0F))[(net * 8 + t) * 64 + lane] = v;
    }
  }
}

// ---------------------------- main kernel ----------------------------------
extern "C" __global__ void __launch_bounds__(512, 4)
gcnn_critic_kernel(const float* __restrict__ obs, const float* __restrict__ act,
                   const float* __restrict__ b0a, const float* __restrict__ b1a,
                   const float* __restrict__ w2a, const float* __restrict__ b2a,
                   const float* __restrict__ b0b, const float* __restrict__ b1b,
                   const float* __restrict__ w2b, const float* __restrict__ b2b,
                   const unsigned short* __restrict__ ws,
                   float* __restrict__ out) {
  extern __shared__ char smem[];
  const int tid  = threadIdx.x;
  const int lane = tid & 63;
  const int wv   = tid >> 6;
  const int l15  = lane & 15;
  const int lg   = lane >> 4;
  const int net  = blockIdx.x & 1;
  const int batch = (blockIdx.x >> 1) * 8 + wv;  // one batch per wave

  s16x8* lW = (s16x8*)smem;                  // 2048 fragments (32KB)
  float* raw = (float*)(smem + LDS_RAW) + wv * 200;

  // ---- cooperative stage: this net's W1 fragments into LDS (32KB) ----
  {
    const s16x8* gW = (const s16x8*)(ws + WS_W1) + net * 2048;
#pragma unroll
    for (int k = 0; k < 4; ++k) lW[tid + k * 512] = gW[tid + k * 512];
  }
  // stage raw features: [0..159]=obs row, [160..191]=action row
#pragma unroll
  for (int i = 0; i < 3; ++i) {
    int j = i * 64 + lane;
    if (j < 192) {
      float v = (j < 160) ? obs[batch * 160 + j] : act[batch * 32 + (j - 160)];
      raw[j] = v;
    }
  }
  __syncthreads();

  // --- adjacency (per-lane): Af[j] = A[d=l15][s=4lg+j] ; symmetric ---
  float wreg[4];
  float wsum = 0.f;
#pragma unroll
  for (int j = 0; j < 4; ++j) {
    int s = 4 * lg + j;
    float dx = raw[l15 * 10]     - raw[s * 10];
    float dy = raw[l15 * 10 + 1] - raw[s * 10 + 1];
    float w = expf(-sqrtf(dx * dx + dy * dy));
    wreg[j] = w;
    wsum += w;
  }
  wsum += __shfl_xor(wsum, 16, 64);
  wsum += __shfl_xor(wsum, 32, 64);          // deg[d=l15], all lanes
  float dv = 1.0f / sqrtf(wsum);             // deg >= 1 (self loop)
  float Af[4];
#pragma unroll
  for (int j = 0; j < 4; ++j) {
    float dvs = __shfl(dv, 4 * lg + j, 64);  // dinv[s]
    Af[j] = wreg[j] * dv * dvs;
  }
  unsigned AH01, AL01, AH23, AL23;
  split_pk(Af[0], Af[1], AH01, AL01);
  split_pk(Af[2], Af[3], AH23, AL23);
  const s16x8 ABh = as_s16x8((u32x4){AH01, AH23, AH01, AH23});
  const s16x8 ABl = as_s16x8((u32x4){AL01, AL23, 0u, 0u});

  // --- x^T A-fragment: x[src=4lg+j][feat=l15], split hi/lo ---
  float xv[4];
#pragma unroll
  for (int j = 0; j < 4; ++j) {
    int s = 4 * lg + j;
    float v = 0.f;
    if (l15 < 8)       v = raw[s * 10 + 2 + l15];
    else if (l15 < 10) v = raw[160 + s * 2 + (l15 - 8)];
    xv[j] = v;
  }
  unsigned xH0, xL0, xH1, xL1;
  split_pk(xv[0], xv[1], xH0, xL0);
  split_pk(xv[2], xv[3], xH1, xL1);
  const s16x8 xop = as_s16x8((u32x4){xH0, xH1, xL0, xL1});

  // --- z0^T = x^T @ A : D-frag == A-frag of layer 1 ---
  f32x4 z0 = {0.f, 0.f, 0.f, 0.f};
  z0 = MFMA32(xop, ABh, z0);   // xh*Ah + xl*Ah
  z0 = MFMA32(xop, ABl, z0);   // xh*Al
  unsigned zH0, zL0, zH1, zL1;
  split_pk(z0[0], z0[1], zH0, zL0);
  split_pk(z0[2], z0[3], zH1, zL1);
  const s16x8 z0op = as_s16x8((u32x4){zH0, zH1, zL0, zL1});

  const s16x8* W0F = (const s16x8*)(ws + WS_W0F);
  const float* B0 = net ? b0b : b0a;
  const float* B1 = net ? b1b : b1a;
  const float* W2 = net ? w2b : w2a;
  const float b2v = net ? b2b[0] : b2a[0];
  const s16x8 zero8 = {0, 0, 0, 0, 0, 0, 0, 0};

  // ---- layer 1: h1 = relu(z0@W0 + b0); D-frag -> mix A-frag, packed ----
  s16x8 h1op[8];
#pragma unroll
  for (int t = 0; t < 8; ++t) {
    s16x8 wf = W0F[(net * 8 + t) * 64 + lane];
    s16x8 Bh = __builtin_shufflevector(wf, wf, 0, 1, 2, 3, 0, 1, 2, 3);
    s16x8 Bl = __builtin_shufflevector(wf, zero8, 4, 5, 6, 7, 8, 9, 10, 11);
    float bv = B0[16 * t + l15];
    f32x4 a = {0.f, 0.f, 0.f, 0.f};
    a = MFMA32(z0op, Bh, a);
    a = MFMA32(z0op, Bl, a);
    float a0 = fmaxf(a[0] + bv, 0.f), a1 = fmaxf(a[1] + bv, 0.f);
    float a2 = fmaxf(a[2] + bv, 0.f), a3 = fmaxf(a[3] + bv, 0.f);
    unsigned H0, L0, H1, L1;
    split_pk(a0, a1, H0, L0);
    split_pk(a2, a3, H1, L1);
    h1op[t] = as_s16x8((u32x4){H0, H1, L0, L1});
  }

  // ---- mix: z1^T_t = h1_t^T @ A ; D-frag -> layer-2 A-frag, packed ----
  unsigned zHw[8][2], zLw[8][2];
#pragma unroll
  for (int t = 0; t < 8; ++t) {
    f32x4 z = {0.f, 0.f, 0.f, 0.f};
    z = MFMA32(h1op[t], ABh, z);
    z = MFMA32(h1op[t], ABl, z);
    split_pk(z[0], z[1], zHw[t][0], zLw[t][0]);
    split_pk(z[2], z[3], zHw[t][1], zLw[t][1]);
  }

  // ---- layer 2: h2 = relu(z1@W1 + b1); W1 single bf16, z split hi+lo ----
  f32x4 acc[8];
#pragma unroll
  for (int t = 0; t < 8; ++t) acc[t] = (f32x4){0.f, 0.f, 0.f, 0.f};
  __builtin_amdgcn_s_setprio(1);
#pragma unroll
  for (int q = 0; q < 4; ++q) {
    s16x8 zh8 = as_s16x8(
        (u32x4){zHw[2 * q][0], zHw[2 * q][1], zHw[2 * q + 1][0], zHw[2 * q + 1][1]});
    s16x8 zl8 = as_s16x8(
        (u32x4){zLw[2 * q][0], zLw[2 * q][1], zLw[2 * q + 1][0], zLw[2 * q + 1][1]});
    int base = (q * 8) * 64 + lane;
#pragma unroll
    for (int t = 0; t < 8; ++t) {
      s16x8 W = lW[base + t * 64];
      acc[t] = MFMA32(zh8, W, acc[t]);
      acc[t] = MFMA32(zl8, W, acc[t]);
    }
  }
  __builtin_amdgcn_s_setprio(0);

  // ---- layer 3: s[node] = sum_c relu(h2+b1)*W2 ; q = A@s + b2 ----
  float part[4] = {0.f, 0.f, 0.f, 0.f};
#pragma unroll
  for (int t = 0; t < 8; ++t) {
    float bv  = B1[16 * t + l15];
    float wv2 = W2[16 * t + l15];
#pragma unroll
    for (int r = 0; r < 4; ++r)
      part[r] += fmaxf(acc[t][r] + bv, 0.f) * wv2;
  }
#pragma unroll
  for (int d = 1; d < 16; d <<= 1)
#pragma unroll
    for (int r = 0; r < 4; ++r)
      part[r] += __shfl_xor(part[r], d, 64);
  // part[j] = s[node=4lg+j] (all l15). q[d=l15] = sum_s A[l15][s]*s[s]
  float pq = Af[0] * part[0] + Af[1] * part[1] + Af[2] * part[2] + Af[3] * part[3];
  pq += __shfl_xor(pq, 16, 64);
  pq += __shfl_xor(pq, 32, 64);
  if (lane < 16)
    out[net * 65536 + batch * 16 + l15] = pq + b2v;
}

extern "C" void kernel_launch(void* const* d_in, const int* in_sizes, int n_in,
                              void* d_out, int out_size, void* d_ws, size_t ws_size,
                              hipStream_t stream) {
  (void)in_sizes; (void)n_in; (void)out_size; (void)ws_size;
  const float* obs = (const float*)d_in[0];
  const float* act = (const float*)d_in[1];
  const float* w0a = (const float*)d_in[2];
  const float* b0a = (const float*)d_in[3];
  const float* w1a = (const float*)d_in[4];
  const float* b1a = (const float*)d_in[5];
  const float* w2a = (const float*)d_in[6];
  const float* b2a = (const float*)d_in[7];
  const float* w0b = (const float*)d_in[8];
  const float* b0b = (const float*)d_in[9];
  const float* w1b = (const float*)d_in[10];
  const float* b1b = (const float*)d_in[11];
  const float* w2b = (const float*)d_in[12];
  const float* b2b = (const float*)d_in[13];
  unsigned short* ws = (unsigned short*)d_ws;

  prep_weights<<<17, 256, 0, stream>>>(w0a, w1a, w0b, w1b, ws);
  gcnn_critic_kernel<<<1024, 512, SMEM_TOTAL, stream>>>(
      obs, act, b0a, b1a, w2a, b2a, b0b, b1b, w2b, b2b, ws, (float*)d_out);
}